// Round 8
// baseline (178.356 us; speedup 1.0000x reference)
//
#include <hip/hip_runtime.h>
#include <math.h>

#define D_IN 768
#define E_DIM 256
#define NB 32
#define NP 192
#define NA 30

#define A_SLOTS (452 * 24 * 64)          // 694,272
#define B_SLOTS (4 * 16 * 24 * 64)       // 98,304

typedef __attribute__((ext_vector_type(8))) __bf16 bf16x8;
typedef __attribute__((ext_vector_type(4))) float f32x4;

__device__ __forceinline__ bf16x8 cvt8(float4 a, float4 b) {
    bf16x8 v;
    v[0]=(__bf16)a.x; v[1]=(__bf16)a.y; v[2]=(__bf16)a.z; v[3]=(__bf16)a.w;
    v[4]=(__bf16)b.x; v[5]=(__bf16)b.y; v[6]=(__bf16)b.z; v[7]=(__bf16)b.w;
    return v;
}

// ---------------------------------------------------------------------------
// Prepack: fp32 sources -> bf16 MFMA fragment layouts; zeroes out_pm/out_am.
// ---------------------------------------------------------------------------
__global__ __launch_bounds__(256) void prepack_kernel(
    const float* __restrict__ vf, const float* __restrict__ tf,
    const float* __restrict__ Wp, const float* __restrict__ Wa,
    const float* __restrict__ Wv, const float* __restrict__ Wt,
    __bf16* __restrict__ Apack, __bf16* __restrict__ Bpack,
    float* __restrict__ out_zero)
{
    const int s = blockIdx.x * 256 + threadIdx.x;
    if (s < 16384) out_zero[s] = 0.f;    // out_pm + out_am
    if (s < A_SLOTS) {
        const int r16 = s / 1536;
        const int rem = s - r16 * 1536;
        const int kt = rem >> 6, l = rem & 63;
        const int row16 = l & 15;
        const int k0 = kt * 32 + (l >> 4) * 8;
        const float* src;
        if (r16 < 384) {
            const int v = r16 / 12, sub = r16 - 12 * v;
            src = vf + (size_t)(v * 193 + 1 + sub * 16 + row16) * D_IN;
        } else if (r16 < 448) {
            const int u = r16 - 384, t = u >> 1, half = u & 1;
            const int ridx = half * 16 + row16;
            const int r = (ridx < NA) ? ridx : 0;
            src = tf + (size_t)(t * 31 + 1 + r) * D_IN;
        } else if (r16 < 450) {
            src = vf + (size_t)((r16 - 448) * 16 + row16) * 193 * D_IN;
        } else {
            src = tf + (size_t)((r16 - 450) * 16 + row16) * 31 * D_IN;
        }
        float4 f0 = *(const float4*)&src[k0];
        float4 f1 = *(const float4*)&src[k0 + 4];
        *(bf16x8*)&Apack[(size_t)s * 8] = cvt8(f0, f1);
    } else {
        const int u = s - A_SLOTS;
        const int mat = u / 24576;
        const int rem = u - mat * 24576;
        const int ntile = rem / 1536;
        const int rem2 = rem - ntile * 1536;
        const int kt = rem2 >> 6, l = rem2 & 63;
        const float* W;
        if (mat == 0)      W = Wp;
        else if (mat == 1) W = Wa;
        else if (mat == 2) W = Wv;
        else               W = Wt;
        const int k0 = kt * 32 + (l >> 4) * 8;
        const float* src = W + (size_t)(ntile * 16 + (l & 15)) * D_IN;
        float4 f0 = *(const float4*)&src[k0];
        float4 f1 = *(const float4*)&src[k0 + 4];
        *(bf16x8*)&Bpack[(size_t)u * 8] = cvt8(f0, f1);
    }
}

// ---------------------------------------------------------------------------
// Fused GEMM+pack v2: 452 blocks x 512 threads. K split across wave halves
// (waves 0-3: K[0,384), waves 4-7: K[384,768)), combined in LDS.
// Then bias/norms/means/embeds + bf16 frag packs.
// ---------------------------------------------------------------------------
__global__ __launch_bounds__(512) void gemm_pack_kernel(
    const __bf16* __restrict__ Apack, const __bf16* __restrict__ Bpack,
    const float* __restrict__ bv, const float* __restrict__ bt,
    const float* __restrict__ bp, const float* __restrict__ ba,
    const int* __restrict__ att_nums,
    float* __restrict__ out_vis, float* __restrict__ out_txt,
    float* __restrict__ out_pm, float* __restrict__ out_am,
    __bf16* __restrict__ pn_frag, __bf16* __restrict__ pB_frag,
    __bf16* __restrict__ an_frag, __bf16* __restrict__ attT_frag)
{
    __shared__ float LDSf[16 * 260];
    __shared__ float LDSp[16 * 260];
    __shared__ float invn_s[16];

    const int r16 = blockIdx.x;
    const int tid = threadIdx.x;
    const int w = tid >> 6, l = tid & 63, q = l >> 4, n15 = l & 15;
    const int kh = w >> 2, wq = w & 3;
    const int mat = (r16 < 384) ? 0 : (r16 < 448) ? 1 : (r16 < 450) ? 2 : 3;
    const float* bias = (mat == 0) ? bp : (mat == 1) ? ba : (mat == 2) ? bv : bt;

    const __bf16* Ab = Apack + (size_t)r16 * 24 * 512 + (size_t)kh * 12 * 512 + l * 8;
    const __bf16* Bb = Bpack + ((size_t)(mat * 16 + wq * 4) * 24 * 512)
                             + (size_t)kh * 12 * 512 + l * 8;

    f32x4 acc[4];
    #pragma unroll
    for (int n = 0; n < 4; ++n) { f32x4 z = {0.f,0.f,0.f,0.f}; acc[n] = z; }

    #pragma unroll 6
    for (int kt = 0; kt < 12; ++kt) {
        bf16x8 a = *(const bf16x8*)&Ab[kt * 512];
        #pragma unroll
        for (int nt = 0; nt < 4; ++nt) {
            bf16x8 b = *(const bf16x8*)&Bb[(size_t)nt * 24 * 512 + kt * 512];
            acc[nt] = __builtin_amdgcn_mfma_f32_16x16x32_bf16(a, b, acc[nt], 0, 0, 0);
        }
    }

    if (kh == 1) {
        #pragma unroll
        for (int nt = 0; nt < 4; ++nt) {
            const int col = wq * 64 + nt * 16 + n15;
            #pragma unroll
            for (int r = 0; r < 4; ++r)
                LDSp[(q * 4 + r) * 260 + col] = acc[nt][r];
        }
    }
    __syncthreads();
    if (kh == 0) {
        #pragma unroll
        for (int nt = 0; nt < 4; ++nt) {
            const int col = wq * 64 + nt * 16 + n15;
            const float b = bias[col];
            #pragma unroll
            for (int r = 0; r < 4; ++r) {
                const int row = q * 4 + r;
                LDSf[row * 260 + col] = acc[nt][r] + LDSp[row * 260 + col] + b;
            }
        }
    }
    __syncthreads();

    if (mat >= 2) {   // embeds: 16 rows x 256 cols, 8 elems/thread
        float* outp = (mat == 2) ? out_vis : out_txt;
        const int rowbase = (mat == 2) ? (r16 - 448) * 16 : (r16 - 450) * 16;
        const int col = tid & 255, rh = tid >> 8;
        #pragma unroll
        for (int i = 0; i < 8; ++i)
            outp[(rowbase + rh * 8 + i) * E_DIM + col] = LDSf[(rh * 8 + i) * 260 + col];
        return;
    }

    const bool is_patch = (mat == 0);
    int vc = 0, mt = 0, t = 0, Av = 1;
    if (is_patch) {
        const int v = r16 / 12, sub = r16 - 12 * v;
        vc = v * 6 + (sub >> 1);  mt = sub & 1;
    } else {
        const int u = r16 - 384;
        t = u >> 1;  mt = u & 1;  Av = att_nums[t];
    }

    // row inv-norms: 32 segs x 8 elems per row
    {
        const int row = tid >> 5, seg = tid & 31;
        const float* rr = &LDSf[row * 260 + seg * 8];
        float ssq = 0.f;
        #pragma unroll
        for (int j = 0; j < 8; ++j) ssq += rr[j] * rr[j];
        ssq += __shfl_xor(ssq, 1, 64);
        ssq += __shfl_xor(ssq, 2, 64);
        ssq += __shfl_xor(ssq, 4, 64);
        ssq += __shfl_xor(ssq, 8, 64);
        ssq += __shfl_xor(ssq, 16, 64);
        if (seg == 0) {
            const bool valid = is_patch || (mt * 16 + row < NA);
            invn_s[row] = valid ? 1.f / fmaxf(sqrtf(ssq), 1e-12f) : 0.f;
        }
    }
    // means (atomic partials)
    if (tid < 256) {
        const int nrows = is_patch ? 16 : (mt == 0 ? 16 : 14);
        float s = 0.f;
        for (int r = 0; r < nrows; ++r) s += LDSf[r * 260 + tid];
        if (is_patch) atomicAdd(&out_pm[(r16 / 12) * E_DIM + tid], s * (1.f / 192.f));
        else          atomicAdd(&out_am[t * E_DIM + tid], s / (float)Av);
    }
    __syncthreads();

    // normalized A-row-frag (512 slots, 1/thread)
    {
        __bf16* dstn = (is_patch ? pn_frag + (size_t)vc * 8192
                                 : an_frag + (size_t)t * 8192) + (size_t)mt * 4096;
        const int s2 = tid;
        const int koct = s2 >> 6, lane = s2 & 63;
        const int rloc = lane & 15;
        const int e0 = koct * 32 + (lane >> 4) * 8;
        const float inr = invn_s[rloc];
        const float* src = &LDSf[rloc * 260 + e0];
        bf16x8 vv;
        #pragma unroll
        for (int j = 0; j < 8; ++j) vv[j] = (__bf16)(src[j] * inr);
        *(bf16x8*)&dstn[(size_t)s2 * 8] = vv;
    }
    // raw B-frag (k=row): 512 slots, 1/thread
    {
        __bf16* dstb = is_patch ? pB_frag + (size_t)vc * 8192
                                : attT_frag + (size_t)t * 8192;
        const int s2 = tid;
        const int nt = s2 >> 5, li = s2 & 31;
        const int lane = 32 * mt + li;
        const int p0 = (li >> 4) * 8;
        const int e = nt * 16 + (li & 15);
        bf16x8 vv;
        #pragma unroll
        for (int j = 0; j < 8; ++j) {
            float val = LDSf[(p0 + j) * 260 + e];
            if (!is_patch && (mt * 16 + p0 + j >= NA)) val = 0.f;
            vv[j] = (__bf16)val;
        }
        *(bf16x8*)&dstb[(size_t)(nt * 64 + lane) * 8] = vv;
    }
}

// ---------------------------------------------------------------------------
// Pair kernel v4: one block per (v,t). 2 chunks per iteration, X double-
// buffered; aa rows wave-local (wave = (chunk-parity, m-half), aacc[16]):
// row norms are in-wave -> 2 barriers per iteration, no per-chunk LDS
// reduction. ap keeps e-split mapping (cross-wave norm once at end).
// ---------------------------------------------------------------------------
__global__ __launch_bounds__(256, 3) void pair_mfma_kernel(
    const __bf16* __restrict__ pn_frag, const __bf16* __restrict__ pB_frag,
    const __bf16* __restrict__ an_frag, const __bf16* __restrict__ attT_frag,
    const int* __restrict__ att_nums, float* __restrict__ out_sim)
{
    __shared__ __align__(16) __bf16 an_s[8192];
    __shared__ __align__(16) __bf16 Xa_s[2][1024];
    __shared__ __align__(16) __bf16 XaT_s[2][1024];
    __shared__ float red_s[128];
    __shared__ float sp_s[256];
    __shared__ float wred_s[4];

    const int v = blockIdx.x, t = blockIdx.y;
    const int tid = threadIdx.x;
    const int w = tid >> 6, l = tid & 63, q = l >> 4, n15 = l & 15;
    const int Av = att_nums[t];
    const int mt = w >> 1, at = w & 1;    // score roles
    const int cp = w >> 1, mtx = w & 1;   // aa roles

    {
        const __bf16* s1 = an_frag + (size_t)t * 8192;
        #pragma unroll
        for (int i = 0; i < 4; ++i) {
            const int slot = tid + 256 * i;
            *(bf16x8*)&an_s[slot * 8] = *(const bf16x8*)&s1[slot * 8];
        }
    }
    __syncthreads();

    const __bf16* atb = attT_frag + (size_t)t * 8192;

    f32x4 apacc[2][4];
    #pragma unroll
    for (int m = 0; m < 2; ++m)
        #pragma unroll
        for (int n = 0; n < 4; ++n) { f32x4 z = {0.f,0.f,0.f,0.f}; apacc[m][n] = z; }
    float sa_acc[16];
    #pragma unroll
    for (int n = 0; n < 16; ++n) sa_acc[n] = 0.f;

    for (int i = 0; i < 3; ++i) {
        // ---- score both chunks: X = exp(relu(20*cos)), write both layouts ----
        #pragma unroll
        for (int cc = 0; cc < 2; ++cc) {
            const __bf16* pnb = pn_frag + (size_t)(v * 6 + 2 * i + cc) * 8192;
            f32x4 sacc = {0.f, 0.f, 0.f, 0.f};
            #pragma unroll
            for (int kp = 0; kp < 8; ++kp) {
                bf16x8 af  = *(const bf16x8*)&pnb[((mt * 8 + kp) * 64 + l) * 8];
                bf16x8 bf_ = *(const bf16x8*)&an_s[((at * 8 + kp) * 64 + l) * 8];
                sacc = __builtin_amdgcn_mfma_f32_16x16x32_bf16(af, bf_, sacc, 0, 0, 0);
            }
            const int a = at * 16 + n15;
            #pragma unroll
            for (int r = 0; r < 4; ++r) {
                const int pcl = q * 4 + r;
                const int pcc = mt * 16 + pcl;
                float xvv = (a < Av) ? __expf(fmaxf(20.f * sacc[r], 0.f)) : 0.f;
                __bf16 h = (__bf16)xvv;
                Xa_s[cc][mt * 512 + (pcl + 16 * (a >> 3)) * 8 + (a & 7)] = h;
                XaT_s[cc][at * 512 + (n15 + 16 * (pcc >> 3)) * 8 + (pcc & 7)] = h;
            }
        }
        __syncthreads();   // X buffers ready

        // ---- aa: wave-local rows (chunk cp, m-half mtx), full 256 e ----
        {
            bf16x8 xa = *(const bf16x8*)&Xa_s[cp][mtx * 512 + l * 8];
            f32x4 aacc[16];
            #pragma unroll
            for (int nt = 0; nt < 16; ++nt) {
                bf16x8 ab = *(const bf16x8*)&atb[(nt * 64 + l) * 8];
                f32x4 z = {0.f, 0.f, 0.f, 0.f};
                aacc[nt] = __builtin_amdgcn_mfma_f32_16x16x32_bf16(xa, ab, z, 0, 0, 0);
            }
            #pragma unroll
            for (int r = 0; r < 4; ++r) {
                float ssq = 0.f;
                #pragma unroll
                for (int nt = 0; nt < 16; ++nt) ssq += aacc[nt][r] * aacc[nt][r];
                ssq += __shfl_xor(ssq, 1, 64);
                ssq += __shfl_xor(ssq, 2, 64);
                ssq += __shfl_xor(ssq, 4, 64);
                ssq += __shfl_xor(ssq, 8, 64);
                const float inr = 1.f / fmaxf(sqrtf(ssq), 1e-12f);
                #pragma unroll
                for (int nt = 0; nt < 16; ++nt) sa_acc[nt] += aacc[nt][r] * inr;
            }
        }
        // ---- ap: e-split (4 e-tiles per wave), both chunks ----
        #pragma unroll
        for (int cp2 = 0; cp2 < 2; ++cp2) {
            const __bf16* pbb = pB_frag + (size_t)(v * 6 + 2 * i + cp2) * 8192;
            bf16x8 xt0 = *(const bf16x8*)&XaT_s[cp2][l * 8];
            bf16x8 xt1 = *(const bf16x8*)&XaT_s[cp2][512 + l * 8];
            #pragma unroll
            for (int nt = 0; nt < 4; ++nt) {
                bf16x8 pbv = *(const bf16x8*)&pbb[((w * 4 + nt) * 64 + l) * 8];
                apacc[0][nt] = __builtin_amdgcn_mfma_f32_16x16x32_bf16(xt0, pbv, apacc[0][nt], 0, 0, 0);
                apacc[1][nt] = __builtin_amdgcn_mfma_f32_16x16x32_bf16(xt1, pbv, apacc[1][nt], 0, 0, 0);
            }
        }
        __syncthreads();   // X consumed; next iter may overwrite
    }

    // ---- ap row norms (cross-wave, once) ----
    #pragma unroll
    for (int atx = 0; atx < 2; ++atx)
        #pragma unroll
        for (int r = 0; r < 4; ++r) {
            float ssq = 0.f;
            #pragma unroll
            for (int nt = 0; nt < 4; ++nt) { float vv = apacc[atx][nt][r]; ssq += vv * vv; }
            ssq += __shfl_xor(ssq, 1, 64);
            ssq += __shfl_xor(ssq, 2, 64);
            ssq += __shfl_xor(ssq, 4, 64);
            ssq += __shfl_xor(ssq, 8, 64);
            if (n15 == 0) red_s[(atx * 16 + q * 4 + r) * 4 + w] = ssq;
        }
    __syncthreads();
    float inr_ap[2][4];
    #pragma unroll
    for (int atx = 0; atx < 2; ++atx)
        #pragma unroll
        for (int r = 0; r < 4; ++r) {
            const int row = atx * 16 + q * 4 + r;
            const float s = red_s[row * 4] + red_s[row * 4 + 1]
                          + red_s[row * 4 + 2] + red_s[row * 4 + 3];
            inr_ap[atx][r] = 1.f / fmaxf(sqrtf(s), 1e-12f);
        }

    // ---- sp vector (per-wave 4 e-tiles) -> sp_s ----
    #pragma unroll
    for (int nt = 0; nt < 4; ++nt) {
        float sp = 0.f;
        #pragma unroll
        for (int atx = 0; atx < 2; ++atx)
            #pragma unroll
            for (int r = 0; r < 4; ++r)
                sp += apacc[atx][nt][r] * inr_ap[atx][r];
        sp += __shfl_xor(sp, 16, 64);
        sp += __shfl_xor(sp, 32, 64);
        if (q == 0) sp_s[(w * 4 + nt) * 16 + n15] = sp;
    }
    // sa: reduce over q groups (rows within wave)
    #pragma unroll
    for (int nt = 0; nt < 16; ++nt) {
        sa_acc[nt] += __shfl_xor(sa_acc[nt], 16, 64);
        sa_acc[nt] += __shfl_xor(sa_acc[nt], 32, 64);
    }
    __syncthreads();

    // ---- rank-1 contraction ----
    float prod = 0.f;
    #pragma unroll
    for (int nt = 0; nt < 16; ++nt)
        prod += sa_acc[nt] * sp_s[nt * 16 + n15];
    prod += __shfl_xor(prod, 1, 64);
    prod += __shfl_xor(prod, 2, 64);
    prod += __shfl_xor(prod, 4, 64);
    prod += __shfl_xor(prod, 8, 64);
    if (l == 0) wred_s[w] = prod;
    __syncthreads();
    if (tid == 0)
        out_sim[t * NB + v] = (wred_s[0] + wred_s[1] + wred_s[2] + wred_s[3])
                              / ((float)Av * 30.f);
}

// ---------------------------------------------------------------------------
extern "C" void kernel_launch(void* const* d_in, const int* in_sizes, int n_in,
                              void* d_out, int out_size, void* d_ws, size_t ws_size,
                              hipStream_t stream)
{
    const float* vf = (const float*)d_in[0];
    const float* tf = (const float*)d_in[1];
    const int*   an = (const int*)d_in[3];
    const float* Wv = (const float*)d_in[4];
    const float* bv = (const float*)d_in[5];
    const float* Wt = (const float*)d_in[6];
    const float* bt = (const float*)d_in[7];
    const float* Wp = (const float*)d_in[8];
    const float* bp = (const float*)d_in[9];
    const float* Wa = (const float*)d_in[10];
    const float* ba = (const float*)d_in[11];

    float* out = (float*)d_out;
    float* out_vis = out;
    float* out_txt = out + 8192;
    float* out_pm  = out + 16384;
    float* out_am  = out + 24576;
    float* out_sim = out + 32768;

    __bf16* Apack = (__bf16*)d_ws;
    __bf16* Bpack = Apack + (size_t)A_SLOTS * 8;
    __bf16* frag0 = Bpack + (size_t)B_SLOTS * 8;
    __bf16* pn_frag   = frag0;
    __bf16* pB_frag   = frag0 + 1572864;
    __bf16* an_frag   = frag0 + 3145728;
    __bf16* attT_frag = frag0 + 3407872;

    prepack_kernel<<<(A_SLOTS + B_SLOTS) / 256, 256, 0, stream>>>(
        vf, tf, Wp, Wa, Wv, Wt, Apack, Bpack, out + 16384);

    gemm_pack_kernel<<<452, 512, 0, stream>>>(
        Apack, Bpack, bv, bt, bp, ba, an,
        out_vis, out_txt, out_pm, out_am,
        pn_frag, pB_frag, an_frag, attT_frag);

    pair_mfma_kernel<<<dim3(NB, NB), 256, 0, stream>>>(
        pn_frag, pB_frag, an_frag, attT_frag, an, out_sim);
}

// Round 9
// 138.471 us; speedup vs baseline: 1.2880x; 1.2880x over previous
//
#include <hip/hip_runtime.h>
#include <math.h>

#define D_IN 768
#define E_DIM 256
#define NB 32
#define NP 192
#define NA 30

#define A_SLOTS (452 * 24 * 64)          // 694,272
#define B_SLOTS (4 * 16 * 24 * 64)       // 98,304

typedef __attribute__((ext_vector_type(8))) __bf16 bf16x8;
typedef __attribute__((ext_vector_type(4))) float f32x4;

__device__ __forceinline__ bf16x8 cvt8(float4 a, float4 b) {
    bf16x8 v;
    v[0]=(__bf16)a.x; v[1]=(__bf16)a.y; v[2]=(__bf16)a.z; v[3]=(__bf16)a.w;
    v[4]=(__bf16)b.x; v[5]=(__bf16)b.y; v[6]=(__bf16)b.z; v[7]=(__bf16)b.w;
    return v;
}

// ---------------------------------------------------------------------------
// Prepack: fp32 sources -> bf16 MFMA fragment layouts; zeroes out_pm/out_am.
// ---------------------------------------------------------------------------
__global__ __launch_bounds__(256) void prepack_kernel(
    const float* __restrict__ vf, const float* __restrict__ tf,
    const float* __restrict__ Wp, const float* __restrict__ Wa,
    const float* __restrict__ Wv, const float* __restrict__ Wt,
    __bf16* __restrict__ Apack, __bf16* __restrict__ Bpack,
    float* __restrict__ out_zero)
{
    const int s = blockIdx.x * 256 + threadIdx.x;
    if (s < 16384) out_zero[s] = 0.f;    // out_pm + out_am
    if (s < A_SLOTS) {
        const int r16 = s / 1536;
        const int rem = s - r16 * 1536;
        const int kt = rem >> 6, l = rem & 63;
        const int row16 = l & 15;
        const int k0 = kt * 32 + (l >> 4) * 8;
        const float* src;
        if (r16 < 384) {
            const int v = r16 / 12, sub = r16 - 12 * v;
            src = vf + (size_t)(v * 193 + 1 + sub * 16 + row16) * D_IN;
        } else if (r16 < 448) {
            const int u = r16 - 384, t = u >> 1, half = u & 1;
            const int ridx = half * 16 + row16;
            const int r = (ridx < NA) ? ridx : 0;
            src = tf + (size_t)(t * 31 + 1 + r) * D_IN;
        } else if (r16 < 450) {
            src = vf + (size_t)((r16 - 448) * 16 + row16) * 193 * D_IN;
        } else {
            src = tf + (size_t)((r16 - 450) * 16 + row16) * 31 * D_IN;
        }
        float4 f0 = *(const float4*)&src[k0];
        float4 f1 = *(const float4*)&src[k0 + 4];
        *(bf16x8*)&Apack[(size_t)s * 8] = cvt8(f0, f1);
    } else {
        const int u = s - A_SLOTS;
        const int mat = u / 24576;
        const int rem = u - mat * 24576;
        const int ntile = rem / 1536;
        const int rem2 = rem - ntile * 1536;
        const int kt = rem2 >> 6, l = rem2 & 63;
        const float* W;
        if (mat == 0)      W = Wp;
        else if (mat == 1) W = Wa;
        else if (mat == 2) W = Wv;
        else               W = Wt;
        const int k0 = kt * 32 + (l >> 4) * 8;
        const float* src = W + (size_t)(ntile * 16 + (l & 15)) * D_IN;
        float4 f0 = *(const float4*)&src[k0];
        float4 f1 = *(const float4*)&src[k0 + 4];
        *(bf16x8*)&Bpack[(size_t)u * 8] = cvt8(f0, f1);
    }
}

// ---------------------------------------------------------------------------
// Fused GEMM+pack: 452 blocks x 512 threads, K split across wave halves,
// combined in LDS; then bias/norms/means/embeds + bf16 frag packs.
// ---------------------------------------------------------------------------
__global__ __launch_bounds__(512) void gemm_pack_kernel(
    const __bf16* __restrict__ Apack, const __bf16* __restrict__ Bpack,
    const float* __restrict__ bv, const float* __restrict__ bt,
    const float* __restrict__ bp, const float* __restrict__ ba,
    const int* __restrict__ att_nums,
    float* __restrict__ out_vis, float* __restrict__ out_txt,
    float* __restrict__ out_pm, float* __restrict__ out_am,
    __bf16* __restrict__ pn_frag, __bf16* __restrict__ pB_frag,
    __bf16* __restrict__ an_frag, __bf16* __restrict__ attT_frag)
{
    __shared__ float LDSf[16 * 260];
    __shared__ float LDSp[16 * 260];
    __shared__ float invn_s[16];

    const int r16 = blockIdx.x;
    const int tid = threadIdx.x;
    const int w = tid >> 6, l = tid & 63, q = l >> 4, n15 = l & 15;
    const int kh = w >> 2, wq = w & 3;
    const int mat = (r16 < 384) ? 0 : (r16 < 448) ? 1 : (r16 < 450) ? 2 : 3;
    const float* bias = (mat == 0) ? bp : (mat == 1) ? ba : (mat == 2) ? bv : bt;

    const __bf16* Ab = Apack + (size_t)r16 * 24 * 512 + (size_t)kh * 12 * 512 + l * 8;
    const __bf16* Bb = Bpack + ((size_t)(mat * 16 + wq * 4) * 24 * 512)
                             + (size_t)kh * 12 * 512 + l * 8;

    f32x4 acc[4];
    #pragma unroll
    for (int n = 0; n < 4; ++n) { f32x4 z = {0.f,0.f,0.f,0.f}; acc[n] = z; }

    #pragma unroll 6
    for (int kt = 0; kt < 12; ++kt) {
        bf16x8 a = *(const bf16x8*)&Ab[kt * 512];
        #pragma unroll
        for (int nt = 0; nt < 4; ++nt) {
            bf16x8 b = *(const bf16x8*)&Bb[(size_t)nt * 24 * 512 + kt * 512];
            acc[nt] = __builtin_amdgcn_mfma_f32_16x16x32_bf16(a, b, acc[nt], 0, 0, 0);
        }
    }

    if (kh == 1) {
        #pragma unroll
        for (int nt = 0; nt < 4; ++nt) {
            const int col = wq * 64 + nt * 16 + n15;
            #pragma unroll
            for (int r = 0; r < 4; ++r)
                LDSp[(q * 4 + r) * 260 + col] = acc[nt][r];
        }
    }
    __syncthreads();
    if (kh == 0) {
        #pragma unroll
        for (int nt = 0; nt < 4; ++nt) {
            const int col = wq * 64 + nt * 16 + n15;
            const float b = bias[col];
            #pragma unroll
            for (int r = 0; r < 4; ++r) {
                const int row = q * 4 + r;
                LDSf[row * 260 + col] = acc[nt][r] + LDSp[row * 260 + col] + b;
            }
        }
    }
    __syncthreads();

    if (mat >= 2) {
        float* outp = (mat == 2) ? out_vis : out_txt;
        const int rowbase = (mat == 2) ? (r16 - 448) * 16 : (r16 - 450) * 16;
        const int col = tid & 255, rh = tid >> 8;
        #pragma unroll
        for (int i = 0; i < 8; ++i)
            outp[(rowbase + rh * 8 + i) * E_DIM + col] = LDSf[(rh * 8 + i) * 260 + col];
        return;
    }

    const bool is_patch = (mat == 0);
    int vc = 0, mt = 0, t = 0, Av = 1;
    if (is_patch) {
        const int v = r16 / 12, sub = r16 - 12 * v;
        vc = v * 6 + (sub >> 1);  mt = sub & 1;
    } else {
        const int u = r16 - 384;
        t = u >> 1;  mt = u & 1;  Av = att_nums[t];
    }

    {
        const int row = tid >> 5, seg = tid & 31;
        const float* rr = &LDSf[row * 260 + seg * 8];
        float ssq = 0.f;
        #pragma unroll
        for (int j = 0; j < 8; ++j) ssq += rr[j] * rr[j];
        ssq += __shfl_xor(ssq, 1, 64);
        ssq += __shfl_xor(ssq, 2, 64);
        ssq += __shfl_xor(ssq, 4, 64);
        ssq += __shfl_xor(ssq, 8, 64);
        ssq += __shfl_xor(ssq, 16, 64);
        if (seg == 0) {
            const bool valid = is_patch || (mt * 16 + row < NA);
            invn_s[row] = valid ? 1.f / fmaxf(sqrtf(ssq), 1e-12f) : 0.f;
        }
    }
    if (tid < 256) {
        const int nrows = is_patch ? 16 : (mt == 0 ? 16 : 14);
        float s = 0.f;
        for (int r = 0; r < nrows; ++r) s += LDSf[r * 260 + tid];
        if (is_patch) atomicAdd(&out_pm[(r16 / 12) * E_DIM + tid], s * (1.f / 192.f));
        else          atomicAdd(&out_am[t * E_DIM + tid], s / (float)Av);
    }
    __syncthreads();

    {
        __bf16* dstn = (is_patch ? pn_frag + (size_t)vc * 8192
                                 : an_frag + (size_t)t * 8192) + (size_t)mt * 4096;
        const int s2 = tid;
        const int koct = s2 >> 6, lane = s2 & 63;
        const int rloc = lane & 15;
        const int e0 = koct * 32 + (lane >> 4) * 8;
        const float inr = invn_s[rloc];
        const float* src = &LDSf[rloc * 260 + e0];
        bf16x8 vv;
        #pragma unroll
        for (int j = 0; j < 8; ++j) vv[j] = (__bf16)(src[j] * inr);
        *(bf16x8*)&dstn[(size_t)s2 * 8] = vv;
    }
    {
        __bf16* dstb = is_patch ? pB_frag + (size_t)vc * 8192
                                : attT_frag + (size_t)t * 8192;
        const int s2 = tid;
        const int nt = s2 >> 5, li = s2 & 31;
        const int lane = 32 * mt + li;
        const int p0 = (li >> 4) * 8;
        const int e = nt * 16 + (li & 15);
        bf16x8 vv;
        #pragma unroll
        for (int j = 0; j < 8; ++j) {
            float val = LDSf[(p0 + j) * 260 + e];
            if (!is_patch && (mt * 16 + p0 + j >= NA)) val = 0.f;
            vv[j] = (__bf16)val;
        }
        *(bf16x8*)&dstb[(size_t)(nt * 64 + lane) * 8] = vv;
    }
}

// ---------------------------------------------------------------------------
// Pair kernel v5: v4's wave-local aa norms + attT staged in LDS (fixes the
// R8 global re-read blowup). 2 chunks/iter, 2 barriers/iter.
// ---------------------------------------------------------------------------
__global__ __launch_bounds__(256, 3) void pair_mfma_kernel(
    const __bf16* __restrict__ pn_frag, const __bf16* __restrict__ pB_frag,
    const __bf16* __restrict__ an_frag, const __bf16* __restrict__ attT_frag,
    const int* __restrict__ att_nums, float* __restrict__ out_sim)
{
    __shared__ __align__(16) __bf16 an_s[8192];
    __shared__ __align__(16) __bf16 attT_s[8192];
    __shared__ __align__(16) __bf16 Xa_s[2][1024];
    __shared__ __align__(16) __bf16 XaT_s[2][1024];
    __shared__ float red_s[128];
    __shared__ float sp_s[256];
    __shared__ float wred_s[4];

    const int v = blockIdx.x, t = blockIdx.y;
    const int tid = threadIdx.x;
    const int w = tid >> 6, l = tid & 63, q = l >> 4, n15 = l & 15;
    const int Av = att_nums[t];
    const int mt = w >> 1, at = w & 1;    // score roles
    const int cp = w >> 1, mtx = w & 1;   // aa roles

    {
        const __bf16* s1 = an_frag + (size_t)t * 8192;
        const __bf16* s2 = attT_frag + (size_t)t * 8192;
        #pragma unroll
        for (int i = 0; i < 4; ++i) {
            const int slot = tid + 256 * i;
            *(bf16x8*)&an_s[slot * 8]   = *(const bf16x8*)&s1[slot * 8];
            *(bf16x8*)&attT_s[slot * 8] = *(const bf16x8*)&s2[slot * 8];
        }
    }
    __syncthreads();

    f32x4 apacc[2][4];
    #pragma unroll
    for (int m = 0; m < 2; ++m)
        #pragma unroll
        for (int n = 0; n < 4; ++n) { f32x4 z = {0.f,0.f,0.f,0.f}; apacc[m][n] = z; }
    float sa_acc[16];
    #pragma unroll
    for (int n = 0; n < 16; ++n) sa_acc[n] = 0.f;

    for (int i = 0; i < 3; ++i) {
        // ---- score both chunks: X = exp(relu(20*cos)), both frag layouts ----
        #pragma unroll
        for (int cc = 0; cc < 2; ++cc) {
            const __bf16* pnb = pn_frag + (size_t)(v * 6 + 2 * i + cc) * 8192;
            f32x4 sacc = {0.f, 0.f, 0.f, 0.f};
            #pragma unroll
            for (int kp = 0; kp < 8; ++kp) {
                bf16x8 af  = *(const bf16x8*)&pnb[((mt * 8 + kp) * 64 + l) * 8];
                bf16x8 bf_ = *(const bf16x8*)&an_s[((at * 8 + kp) * 64 + l) * 8];
                sacc = __builtin_amdgcn_mfma_f32_16x16x32_bf16(af, bf_, sacc, 0, 0, 0);
            }
            const int a = at * 16 + n15;
            #pragma unroll
            for (int r = 0; r < 4; ++r) {
                const int pcl = q * 4 + r;
                const int pcc = mt * 16 + pcl;
                float xvv = (a < Av) ? __expf(fmaxf(20.f * sacc[r], 0.f)) : 0.f;
                __bf16 h = (__bf16)xvv;
                Xa_s[cc][mt * 512 + (pcl + 16 * (a >> 3)) * 8 + (a & 7)] = h;
                XaT_s[cc][at * 512 + (n15 + 16 * (pcc >> 3)) * 8 + (pcc & 7)] = h;
            }
        }
        __syncthreads();   // X buffers ready

        // ---- aa: wave-local rows (chunk cp, m-half mtx), attT from LDS ----
        {
            bf16x8 xa = *(const bf16x8*)&Xa_s[cp][mtx * 512 + l * 8];
            f32x4 aacc[16];
            #pragma unroll
            for (int nt = 0; nt < 16; ++nt) {
                bf16x8 ab = *(const bf16x8*)&attT_s[(nt * 64 + l) * 8];
                f32x4 z = {0.f, 0.f, 0.f, 0.f};
                aacc[nt] = __builtin_amdgcn_mfma_f32_16x16x32_bf16(xa, ab, z, 0, 0, 0);
            }
            #pragma unroll
            for (int r = 0; r < 4; ++r) {
                float ssq = 0.f;
                #pragma unroll
                for (int nt = 0; nt < 16; ++nt) ssq += aacc[nt][r] * aacc[nt][r];
                ssq += __shfl_xor(ssq, 1, 64);
                ssq += __shfl_xor(ssq, 2, 64);
                ssq += __shfl_xor(ssq, 4, 64);
                ssq += __shfl_xor(ssq, 8, 64);
                const float inr = 1.f / fmaxf(sqrtf(ssq), 1e-12f);
                #pragma unroll
                for (int nt = 0; nt < 16; ++nt) sa_acc[nt] += aacc[nt][r] * inr;
            }
        }
        // ---- ap: e-split (4 e-tiles per wave), both chunks ----
        #pragma unroll
        for (int cp2 = 0; cp2 < 2; ++cp2) {
            const __bf16* pbb = pB_frag + (size_t)(v * 6 + 2 * i + cp2) * 8192;
            bf16x8 xt0 = *(const bf16x8*)&XaT_s[cp2][l * 8];
            bf16x8 xt1 = *(const bf16x8*)&XaT_s[cp2][512 + l * 8];
            #pragma unroll
            for (int nt = 0; nt < 4; ++nt) {
                bf16x8 pbv = *(const bf16x8*)&pbb[((w * 4 + nt) * 64 + l) * 8];
                apacc[0][nt] = __builtin_amdgcn_mfma_f32_16x16x32_bf16(xt0, pbv, apacc[0][nt], 0, 0, 0);
                apacc[1][nt] = __builtin_amdgcn_mfma_f32_16x16x32_bf16(xt1, pbv, apacc[1][nt], 0, 0, 0);
            }
        }
        __syncthreads();   // X consumed; next iter may overwrite
    }

    // ---- ap row norms (cross-wave, once) ----
    #pragma unroll
    for (int atx = 0; atx < 2; ++atx)
        #pragma unroll
        for (int r = 0; r < 4; ++r) {
            float ssq = 0.f;
            #pragma unroll
            for (int nt = 0; nt < 4; ++nt) { float vv = apacc[atx][nt][r]; ssq += vv * vv; }
            ssq += __shfl_xor(ssq, 1, 64);
            ssq += __shfl_xor(ssq, 2, 64);
            ssq += __shfl_xor(ssq, 4, 64);
            ssq += __shfl_xor(ssq, 8, 64);
            if (n15 == 0) red_s[(atx * 16 + q * 4 + r) * 4 + w] = ssq;
        }
    __syncthreads();
    float inr_ap[2][4];
    #pragma unroll
    for (int atx = 0; atx < 2; ++atx)
        #pragma unroll
        for (int r = 0; r < 4; ++r) {
            const int row = atx * 16 + q * 4 + r;
            const float s = red_s[row * 4] + red_s[row * 4 + 1]
                          + red_s[row * 4 + 2] + red_s[row * 4 + 3];
            inr_ap[atx][r] = 1.f / fmaxf(sqrtf(s), 1e-12f);
        }

    // ---- sp vector (per-wave 4 e-tiles) -> sp_s ----
    #pragma unroll
    for (int nt = 0; nt < 4; ++nt) {
        float sp = 0.f;
        #pragma unroll
        for (int atx = 0; atx < 2; ++atx)
            #pragma unroll
            for (int r = 0; r < 4; ++r)
                sp += apacc[atx][nt][r] * inr_ap[atx][r];
        sp += __shfl_xor(sp, 16, 64);
        sp += __shfl_xor(sp, 32, 64);
        if (q == 0) sp_s[(w * 4 + nt) * 16 + n15] = sp;
    }
    // sa: reduce over q groups (rows within wave)
    #pragma unroll
    for (int nt = 0; nt < 16; ++nt) {
        sa_acc[nt] += __shfl_xor(sa_acc[nt], 16, 64);
        sa_acc[nt] += __shfl_xor(sa_acc[nt], 32, 64);
    }
    __syncthreads();

    // ---- rank-1 contraction ----
    float prod = 0.f;
    #pragma unroll
    for (int nt = 0; nt < 16; ++nt)
        prod += sa_acc[nt] * sp_s[nt * 16 + n15];
    prod += __shfl_xor(prod, 1, 64);
    prod += __shfl_xor(prod, 2, 64);
    prod += __shfl_xor(prod, 4, 64);
    prod += __shfl_xor(prod, 8, 64);
    if (l == 0) wred_s[w] = prod;
    __syncthreads();
    if (tid == 0)
        out_sim[t * NB + v] = (wred_s[0] + wred_s[1] + wred_s[2] + wred_s[3])
                              / ((float)Av * 30.f);
}

// ---------------------------------------------------------------------------
extern "C" void kernel_launch(void* const* d_in, const int* in_sizes, int n_in,
                              void* d_out, int out_size, void* d_ws, size_t ws_size,
                              hipStream_t stream)
{
    const float* vf = (const float*)d_in[0];
    const float* tf = (const float*)d_in[1];
    const int*   an = (const int*)d_in[3];
    const float* Wv = (const float*)d_in[4];
    const float* bv = (const float*)d_in[5];
    const float* Wt = (const float*)d_in[6];
    const float* bt = (const float*)d_in[7];
    const float* Wp = (const float*)d_in[8];
    const float* bp = (const float*)d_in[9];
    const float* Wa = (const float*)d_in[10];
    const float* ba = (const float*)d_in[11];

    float* out = (float*)d_out;
    float* out_vis = out;
    float* out_txt = out + 8192;
    float* out_pm  = out + 16384;
    float* out_am  = out + 24576;
    float* out_sim = out + 32768;

    __bf16* Apack = (__bf16*)d_ws;
    __bf16* Bpack = Apack + (size_t)A_SLOTS * 8;
    __bf16* frag0 = Bpack + (size_t)B_SLOTS * 8;
    __bf16* pn_frag   = frag0;
    __bf16* pB_frag   = frag0 + 1572864;
    __bf16* an_frag   = frag0 + 3145728;
    __bf16* attT_frag = frag0 + 3407872;

    prepack_kernel<<<(A_SLOTS + B_SLOTS) / 256, 256, 0, stream>>>(
        vf, tf, Wp, Wa, Wv, Wt, Apack, Bpack, out + 16384);

    gemm_pack_kernel<<<452, 512, 0, stream>>>(
        Apack, Bpack, bv, bt, bp, ba, an,
        out_vis, out_txt, out_pm, out_am,
        pn_frag, pB_frag, an_frag, attT_frag);

    pair_mfma_kernel<<<dim3(NB, NB), 256, 0, stream>>>(
        pn_frag, pB_frag, an_frag, attT_frag, an, out_sim);
}

// Round 10
// 133.196 us; speedup vs baseline: 1.3391x; 1.0396x over previous
//
#include <hip/hip_runtime.h>
#include <math.h>

#define D_IN 768
#define E_DIM 256
#define NB 32
#define NP 192
#define NA 30

#define A_SLOTS (452 * 24 * 64)          // 694,272
#define B_SLOTS (4 * 16 * 24 * 64)       // 98,304

typedef __attribute__((ext_vector_type(8))) __bf16 bf16x8;
typedef __attribute__((ext_vector_type(4))) float f32x4;

__device__ __forceinline__ bf16x8 cvt8(float4 a, float4 b) {
    bf16x8 v;
    v[0]=(__bf16)a.x; v[1]=(__bf16)a.y; v[2]=(__bf16)a.z; v[3]=(__bf16)a.w;
    v[4]=(__bf16)b.x; v[5]=(__bf16)b.y; v[6]=(__bf16)b.z; v[7]=(__bf16)b.w;
    return v;
}

// ---------------------------------------------------------------------------
// Prepack: fp32 sources -> bf16 MFMA fragment layouts; zeroes out_pm/out_am.
// ---------------------------------------------------------------------------
__global__ __launch_bounds__(256) void prepack_kernel(
    const float* __restrict__ vf, const float* __restrict__ tf,
    const float* __restrict__ Wp, const float* __restrict__ Wa,
    const float* __restrict__ Wv, const float* __restrict__ Wt,
    __bf16* __restrict__ Apack, __bf16* __restrict__ Bpack,
    float* __restrict__ out_zero)
{
    const int s = blockIdx.x * 256 + threadIdx.x;
    if (s < 16384) out_zero[s] = 0.f;    // out_pm + out_am
    if (s < A_SLOTS) {
        const int r16 = s / 1536;
        const int rem = s - r16 * 1536;
        const int kt = rem >> 6, l = rem & 63;
        const int row16 = l & 15;
        const int k0 = kt * 32 + (l >> 4) * 8;
        const float* src;
        if (r16 < 384) {
            const int v = r16 / 12, sub = r16 - 12 * v;
            src = vf + (size_t)(v * 193 + 1 + sub * 16 + row16) * D_IN;
        } else if (r16 < 448) {
            const int u = r16 - 384, t = u >> 1, half = u & 1;
            const int ridx = half * 16 + row16;
            const int r = (ridx < NA) ? ridx : 0;
            src = tf + (size_t)(t * 31 + 1 + r) * D_IN;
        } else if (r16 < 450) {
            src = vf + (size_t)((r16 - 448) * 16 + row16) * 193 * D_IN;
        } else {
            src = tf + (size_t)((r16 - 450) * 16 + row16) * 31 * D_IN;
        }
        float4 f0 = *(const float4*)&src[k0];
        float4 f1 = *(const float4*)&src[k0 + 4];
        *(bf16x8*)&Apack[(size_t)s * 8] = cvt8(f0, f1);
    } else {
        const int u = s - A_SLOTS;
        const int mat = u / 24576;
        const int rem = u - mat * 24576;
        const int ntile = rem / 1536;
        const int rem2 = rem - ntile * 1536;
        const int kt = rem2 >> 6, l = rem2 & 63;
        const float* W;
        if (mat == 0)      W = Wp;
        else if (mat == 1) W = Wa;
        else if (mat == 2) W = Wv;
        else               W = Wt;
        const int k0 = kt * 32 + (l >> 4) * 8;
        const float* src = W + (size_t)(ntile * 16 + (l & 15)) * D_IN;
        float4 f0 = *(const float4*)&src[k0];
        float4 f1 = *(const float4*)&src[k0 + 4];
        *(bf16x8*)&Bpack[(size_t)u * 8] = cvt8(f0, f1);
    }
}

// ---------------------------------------------------------------------------
// Fused GEMM+pack: 452 blocks x 512 threads, K split across wave halves,
// combined in LDS; then bias/norms/means/embeds + bf16 frag packs.
// K-loop software-pipelined (depth 2) so loads stay ahead of the MFMA chain.
// ---------------------------------------------------------------------------
__global__ __launch_bounds__(512) void gemm_pack_kernel(
    const __bf16* __restrict__ Apack, const __bf16* __restrict__ Bpack,
    const float* __restrict__ bv, const float* __restrict__ bt,
    const float* __restrict__ bp, const float* __restrict__ ba,
    const int* __restrict__ att_nums,
    float* __restrict__ out_vis, float* __restrict__ out_txt,
    float* __restrict__ out_pm, float* __restrict__ out_am,
    __bf16* __restrict__ pn_frag, __bf16* __restrict__ pB_frag,
    __bf16* __restrict__ an_frag, __bf16* __restrict__ attT_frag)
{
    __shared__ float LDSf[16 * 260];
    __shared__ float LDSp[16 * 260];
    __shared__ float invn_s[16];

    const int r16 = blockIdx.x;
    const int tid = threadIdx.x;
    const int w = tid >> 6, l = tid & 63, q = l >> 4, n15 = l & 15;
    const int kh = w >> 2, wq = w & 3;
    const int mat = (r16 < 384) ? 0 : (r16 < 448) ? 1 : (r16 < 450) ? 2 : 3;
    const float* bias = (mat == 0) ? bp : (mat == 1) ? ba : (mat == 2) ? bv : bt;

    const __bf16* Ab = Apack + (size_t)r16 * 24 * 512 + (size_t)kh * 12 * 512 + l * 8;
    const __bf16* Bb = Bpack + ((size_t)(mat * 16 + wq * 4) * 24 * 512)
                             + (size_t)kh * 12 * 512 + l * 8;

    f32x4 acc[4];
    #pragma unroll
    for (int n = 0; n < 4; ++n) { f32x4 z = {0.f,0.f,0.f,0.f}; acc[n] = z; }

    // depth-2 pipelined K loop
    bf16x8 af[2];
    bf16x8 bfr[2][4];
    af[0] = *(const bf16x8*)&Ab[0];
    #pragma unroll
    for (int nt = 0; nt < 4; ++nt)
        bfr[0][nt] = *(const bf16x8*)&Bb[(size_t)nt * 24 * 512];
    #pragma unroll
    for (int kt = 0; kt < 12; ++kt) {
        const int cur = kt & 1, nxt = cur ^ 1;
        if (kt < 11) {
            af[nxt] = *(const bf16x8*)&Ab[(kt + 1) * 512];
            #pragma unroll
            for (int nt = 0; nt < 4; ++nt)
                bfr[nxt][nt] = *(const bf16x8*)&Bb[(size_t)nt * 24 * 512 + (kt + 1) * 512];
        }
        #pragma unroll
        for (int nt = 0; nt < 4; ++nt)
            acc[nt] = __builtin_amdgcn_mfma_f32_16x16x32_bf16(af[cur], bfr[cur][nt], acc[nt], 0, 0, 0);
    }

    if (kh == 1) {
        #pragma unroll
        for (int nt = 0; nt < 4; ++nt) {
            const int col = wq * 64 + nt * 16 + n15;
            #pragma unroll
            for (int r = 0; r < 4; ++r)
                LDSp[(q * 4 + r) * 260 + col] = acc[nt][r];
        }
    }
    __syncthreads();
    if (kh == 0) {
        #pragma unroll
        for (int nt = 0; nt < 4; ++nt) {
            const int col = wq * 64 + nt * 16 + n15;
            const float b = bias[col];
            #pragma unroll
            for (int r = 0; r < 4; ++r) {
                const int row = q * 4 + r;
                LDSf[row * 260 + col] = acc[nt][r] + LDSp[row * 260 + col] + b;
            }
        }
    }
    __syncthreads();

    if (mat >= 2) {
        float* outp = (mat == 2) ? out_vis : out_txt;
        const int rowbase = (mat == 2) ? (r16 - 448) * 16 : (r16 - 450) * 16;
        const int col = tid & 255, rh = tid >> 8;
        #pragma unroll
        for (int i = 0; i < 8; ++i)
            outp[(rowbase + rh * 8 + i) * E_DIM + col] = LDSf[(rh * 8 + i) * 260 + col];
        return;
    }

    const bool is_patch = (mat == 0);
    int vc = 0, mt = 0, t = 0, Av = 1;
    if (is_patch) {
        const int v = r16 / 12, sub = r16 - 12 * v;
        vc = v * 6 + (sub >> 1);  mt = sub & 1;
    } else {
        const int u = r16 - 384;
        t = u >> 1;  mt = u & 1;  Av = att_nums[t];
    }

    {
        const int row = tid >> 5, seg = tid & 31;
        const float* rr = &LDSf[row * 260 + seg * 8];
        float ssq = 0.f;
        #pragma unroll
        for (int j = 0; j < 8; ++j) ssq += rr[j] * rr[j];
        ssq += __shfl_xor(ssq, 1, 64);
        ssq += __shfl_xor(ssq, 2, 64);
        ssq += __shfl_xor(ssq, 4, 64);
        ssq += __shfl_xor(ssq, 8, 64);
        ssq += __shfl_xor(ssq, 16, 64);
        if (seg == 0) {
            const bool valid = is_patch || (mt * 16 + row < NA);
            invn_s[row] = valid ? 1.f / fmaxf(sqrtf(ssq), 1e-12f) : 0.f;
        }
    }
    if (tid < 256) {
        const int nrows = is_patch ? 16 : (mt == 0 ? 16 : 14);
        float s = 0.f;
        for (int r = 0; r < nrows; ++r) s += LDSf[r * 260 + tid];
        if (is_patch) atomicAdd(&out_pm[(r16 / 12) * E_DIM + tid], s * (1.f / 192.f));
        else          atomicAdd(&out_am[t * E_DIM + tid], s / (float)Av);
    }
    __syncthreads();

    {
        __bf16* dstn = (is_patch ? pn_frag + (size_t)vc * 8192
                                 : an_frag + (size_t)t * 8192) + (size_t)mt * 4096;
        const int s2 = tid;
        const int koct = s2 >> 6, lane = s2 & 63;
        const int rloc = lane & 15;
        const int e0 = koct * 32 + (lane >> 4) * 8;
        const float inr = invn_s[rloc];
        const float* src = &LDSf[rloc * 260 + e0];
        bf16x8 vv;
        #pragma unroll
        for (int j = 0; j < 8; ++j) vv[j] = (__bf16)(src[j] * inr);
        *(bf16x8*)&dstn[(size_t)s2 * 8] = vv;
    }
    {
        __bf16* dstb = is_patch ? pB_frag + (size_t)vc * 8192
                                : attT_frag + (size_t)t * 8192;
        const int s2 = tid;
        const int nt = s2 >> 5, li = s2 & 31;
        const int lane = 32 * mt + li;
        const int p0 = (li >> 4) * 8;
        const int e = nt * 16 + (li & 15);
        bf16x8 vv;
        #pragma unroll
        for (int j = 0; j < 8; ++j) {
            float val = LDSf[(p0 + j) * 260 + e];
            if (!is_patch && (mt * 16 + p0 + j >= NA)) val = 0.f;
            vv[j] = (__bf16)val;
        }
        *(bf16x8*)&dstb[(size_t)(nt * 64 + lane) * 8] = vv;
    }
}

// ---------------------------------------------------------------------------
// Pair kernel v6: v5 + batched register prefetch of all global fragments.
// Score phase: 16 pn loads in flight before the MFMA chains (was 1-at-a-time).
// ap phase: 8 pB loads issued before the (LDS-only) aa phase hides them.
// ---------------------------------------------------------------------------
__global__ __launch_bounds__(256, 3) void pair_mfma_kernel(
    const __bf16* __restrict__ pn_frag, const __bf16* __restrict__ pB_frag,
    const __bf16* __restrict__ an_frag, const __bf16* __restrict__ attT_frag,
    const int* __restrict__ att_nums, float* __restrict__ out_sim)
{
    __shared__ __align__(16) __bf16 an_s[8192];
    __shared__ __align__(16) __bf16 attT_s[8192];
    __shared__ __align__(16) __bf16 Xa_s[2][1024];
    __shared__ __align__(16) __bf16 XaT_s[2][1024];
    __shared__ float red_s[128];
    __shared__ float sp_s[256];
    __shared__ float wred_s[4];

    const int v = blockIdx.x, t = blockIdx.y;
    const int tid = threadIdx.x;
    const int w = tid >> 6, l = tid & 63, q = l >> 4, n15 = l & 15;
    const int Av = att_nums[t];
    const int mt = w >> 1, at = w & 1;    // score roles
    const int cp = w >> 1, mtx = w & 1;   // aa roles

    {
        const __bf16* s1 = an_frag + (size_t)t * 8192;
        const __bf16* s2 = attT_frag + (size_t)t * 8192;
        #pragma unroll
        for (int i = 0; i < 4; ++i) {
            const int slot = tid + 256 * i;
            *(bf16x8*)&an_s[slot * 8]   = *(const bf16x8*)&s1[slot * 8];
            *(bf16x8*)&attT_s[slot * 8] = *(const bf16x8*)&s2[slot * 8];
        }
    }
    __syncthreads();

    f32x4 apacc[2][4];
    #pragma unroll
    for (int m = 0; m < 2; ++m)
        #pragma unroll
        for (int n = 0; n < 4; ++n) { f32x4 z = {0.f,0.f,0.f,0.f}; apacc[m][n] = z; }
    float sa_acc[16];
    #pragma unroll
    for (int n = 0; n < 16; ++n) sa_acc[n] = 0.f;

    for (int i = 0; i < 3; ++i) {
        // ---- prefetch all pn fragments for both chunks (16 loads in flight) ----
        bf16x8 pf[2][8];
        #pragma unroll
        for (int cc = 0; cc < 2; ++cc) {
            const __bf16* pnb = pn_frag + (size_t)(v * 6 + 2 * i + cc) * 8192;
            #pragma unroll
            for (int kp = 0; kp < 8; ++kp)
                pf[cc][kp] = *(const bf16x8*)&pnb[((mt * 8 + kp) * 64 + l) * 8];
        }
        // ---- score both chunks from registers ----
        #pragma unroll
        for (int cc = 0; cc < 2; ++cc) {
            f32x4 sacc = {0.f, 0.f, 0.f, 0.f};
            #pragma unroll
            for (int kp = 0; kp < 8; ++kp) {
                bf16x8 bf_ = *(const bf16x8*)&an_s[((at * 8 + kp) * 64 + l) * 8];
                sacc = __builtin_amdgcn_mfma_f32_16x16x32_bf16(pf[cc][kp], bf_, sacc, 0, 0, 0);
            }
            const int a = at * 16 + n15;
            #pragma unroll
            for (int r = 0; r < 4; ++r) {
                const int pcl = q * 4 + r;
                const int pcc = mt * 16 + pcl;
                float xvv = (a < Av) ? __expf(fmaxf(20.f * sacc[r], 0.f)) : 0.f;
                __bf16 h = (__bf16)xvv;
                Xa_s[cc][mt * 512 + (pcl + 16 * (a >> 3)) * 8 + (a & 7)] = h;
                XaT_s[cc][at * 512 + (n15 + 16 * (pcc >> 3)) * 8 + (pcc & 7)] = h;
            }
        }
        __syncthreads();   // X buffers ready

        // ---- prefetch pB for both chunks (8 loads; latency hides under aa) ----
        bf16x8 pbr[2][4];
        #pragma unroll
        for (int cp2 = 0; cp2 < 2; ++cp2) {
            const __bf16* pbb = pB_frag + (size_t)(v * 6 + 2 * i + cp2) * 8192;
            #pragma unroll
            for (int nt = 0; nt < 4; ++nt)
                pbr[cp2][nt] = *(const bf16x8*)&pbb[((w * 4 + nt) * 64 + l) * 8];
        }

        // ---- aa: wave-local rows (chunk cp, m-half mtx), attT from LDS ----
        {
            bf16x8 xa = *(const bf16x8*)&Xa_s[cp][mtx * 512 + l * 8];
            f32x4 aacc[16];
            #pragma unroll
            for (int nt = 0; nt < 16; ++nt) {
                bf16x8 ab = *(const bf16x8*)&attT_s[(nt * 64 + l) * 8];
                f32x4 z = {0.f, 0.f, 0.f, 0.f};
                aacc[nt] = __builtin_amdgcn_mfma_f32_16x16x32_bf16(xa, ab, z, 0, 0, 0);
            }
            #pragma unroll
            for (int r = 0; r < 4; ++r) {
                float ssq = 0.f;
                #pragma unroll
                for (int nt = 0; nt < 16; ++nt) ssq += aacc[nt][r] * aacc[nt][r];
                ssq += __shfl_xor(ssq, 1, 64);
                ssq += __shfl_xor(ssq, 2, 64);
                ssq += __shfl_xor(ssq, 4, 64);
                ssq += __shfl_xor(ssq, 8, 64);
                const float inr = 1.f / fmaxf(sqrtf(ssq), 1e-12f);
                #pragma unroll
                for (int nt = 0; nt < 16; ++nt) sa_acc[nt] += aacc[nt][r] * inr;
            }
        }
        // ---- ap: e-split (4 e-tiles per wave), both chunks, from registers ----
        #pragma unroll
        for (int cp2 = 0; cp2 < 2; ++cp2) {
            bf16x8 xt0 = *(const bf16x8*)&XaT_s[cp2][l * 8];
            bf16x8 xt1 = *(const bf16x8*)&XaT_s[cp2][512 + l * 8];
            #pragma unroll
            for (int nt = 0; nt < 4; ++nt) {
                apacc[0][nt] = __builtin_amdgcn_mfma_f32_16x16x32_bf16(xt0, pbr[cp2][nt], apacc[0][nt], 0, 0, 0);
                apacc[1][nt] = __builtin_amdgcn_mfma_f32_16x16x32_bf16(xt1, pbr[cp2][nt], apacc[1][nt], 0, 0, 0);
            }
        }
        __syncthreads();   // X consumed; next iter may overwrite
    }

    // ---- ap row norms (cross-wave, once) ----
    #pragma unroll
    for (int atx = 0; atx < 2; ++atx)
        #pragma unroll
        for (int r = 0; r < 4; ++r) {
            float ssq = 0.f;
            #pragma unroll
            for (int nt = 0; nt < 4; ++nt) { float vv = apacc[atx][nt][r]; ssq += vv * vv; }
            ssq += __shfl_xor(ssq, 1, 64);
            ssq += __shfl_xor(ssq, 2, 64);
            ssq += __shfl_xor(ssq, 4, 64);
            ssq += __shfl_xor(ssq, 8, 64);
            if (n15 == 0) red_s[(atx * 16 + q * 4 + r) * 4 + w] = ssq;
        }
    __syncthreads();
    float inr_ap[2][4];
    #pragma unroll
    for (int atx = 0; atx < 2; ++atx)
        #pragma unroll
        for (int r = 0; r < 4; ++r) {
            const int row = atx * 16 + q * 4 + r;
            const float s = red_s[row * 4] + red_s[row * 4 + 1]
                          + red_s[row * 4 + 2] + red_s[row * 4 + 3];
            inr_ap[atx][r] = 1.f / fmaxf(sqrtf(s), 1e-12f);
        }

    // ---- sp vector (per-wave 4 e-tiles) -> sp_s ----
    #pragma unroll
    for (int nt = 0; nt < 4; ++nt) {
        float sp = 0.f;
        #pragma unroll
        for (int atx = 0; atx < 2; ++atx)
            #pragma unroll
            for (int r = 0; r < 4; ++r)
                sp += apacc[atx][nt][r] * inr_ap[atx][r];
        sp += __shfl_xor(sp, 16, 64);
        sp += __shfl_xor(sp, 32, 64);
        if (q == 0) sp_s[(w * 4 + nt) * 16 + n15] = sp;
    }
    // sa: reduce over q groups (rows within wave)
    #pragma unroll
    for (int nt = 0; nt < 16; ++nt) {
        sa_acc[nt] += __shfl_xor(sa_acc[nt], 16, 64);
        sa_acc[nt] += __shfl_xor(sa_acc[nt], 32, 64);
    }
    __syncthreads();

    // ---- rank-1 contraction ----
    float prod = 0.f;
    #pragma unroll
    for (int nt = 0; nt < 16; ++nt)
        prod += sa_acc[nt] * sp_s[nt * 16 + n15];
    prod += __shfl_xor(prod, 1, 64);
    prod += __shfl_xor(prod, 2, 64);
    prod += __shfl_xor(prod, 4, 64);
    prod += __shfl_xor(prod, 8, 64);
    if (l == 0) wred_s[w] = prod;
    __syncthreads();
    if (tid == 0)
        out_sim[t * NB + v] = (wred_s[0] + wred_s[1] + wred_s[2] + wred_s[3])
                              / ((float)Av * 30.f);
}

// ---------------------------------------------------------------------------
extern "C" void kernel_launch(void* const* d_in, const int* in_sizes, int n_in,
                              void* d_out, int out_size, void* d_ws, size_t ws_size,
                              hipStream_t stream)
{
    const float* vf = (const float*)d_in[0];
    const float* tf = (const float*)d_in[1];
    const int*   an = (const int*)d_in[3];
    const float* Wv = (const float*)d_in[4];
    const float* bv = (const float*)d_in[5];
    const float* Wt = (const float*)d_in[6];
    const float* bt = (const float*)d_in[7];
    const float* Wp = (const float*)d_in[8];
    const float* bp = (const float*)d_in[9];
    const float* Wa = (const float*)d_in[10];
    const float* ba = (const float*)d_in[11];

    float* out = (float*)d_out;
    float* out_vis = out;
    float* out_txt = out + 8192;
    float* out_pm  = out + 16384;
    float* out_am  = out + 24576;
    float* out_sim = out + 32768;

    __bf16* Apack = (__bf16*)d_ws;
    __bf16* Bpack = Apack + (size_t)A_SLOTS * 8;
    __bf16* frag0 = Bpack + (size_t)B_SLOTS * 8;
    __bf16* pn_frag   = frag0;
    __bf16* pB_frag   = frag0 + 1572864;
    __bf16* an_frag   = frag0 + 3145728;
    __bf16* attT_frag = frag0 + 3407872;

    prepack_kernel<<<(A_SLOTS + B_SLOTS) / 256, 256, 0, stream>>>(
        vf, tf, Wp, Wa, Wv, Wt, Apack, Bpack, out + 16384);

    gemm_pack_kernel<<<452, 512, 0, stream>>>(
        Apack, Bpack, bv, bt, bp, ba, an,
        out_vis, out_txt, out_pm, out_am,
        pn_frag, pB_frag, an_frag, attT_frag);

    pair_mfma_kernel<<<dim3(NB, NB), 256, 0, stream>>>(
        pn_frag, pB_frag, an_frag, attT_frag, an, out_sim);
}